// Round 5
// baseline (6643.781 us; speedup 1.0000x reference)
//
#include <hip/hip_runtime.h>
#include <cstddef>
#include <cstdint>

// 2-layer LSTM decoder, B=2048, Z=64, H=256, D=8, T=250. fp32 in/out.
//
// R5 = R4 (i8 weight stream, per-column scales, exact i32 MFMA, VGPR
// double-buffered prefetch) + h hi/lo split to kill h-quantization error:
//   h ~= hq/s + lq/(254*s), hq,lq in i8  (15-bit effective h precision)
//   gate = cs * (acc_hi + acc_lo/254) + b, combined in fp32.
// Weights in VGPRs are applied to both A_hi and A_lo -> traffic unchanged
// (768 KB/CU/step), MFMA count x2 (was ~7% util - free).
// R4's 9.77e-3 absmax was h-quant dominated (~3.1e-3 of 3.6e-3 rms gate err);
// removing it leaves w-quant only ~1.5e-3 -> predicted absmax 3-5e-3.

#define BSZ    2048
#define ZDIM   64
#define HDIM   256
#define DDIM   8
#define TSTEPS 250
#define ROWS   16
#define NWG    (BSZ / ROWS)   // 128
#define NTH    512            // 8 waves
#define G4     1024
#define H1STR  264            // h1f/woutT row stride (shorts)

typedef __attribute__((ext_vector_type(4))) int   v4i;

__device__ __forceinline__ unsigned short f2bf(float x) {   // RNE f32->bf16
  union { float f; unsigned u; } v; v.f = x;
  unsigned r = v.u + 0x7fff + ((v.u >> 16) & 1);
  return (unsigned short)(r >> 16);
}
__device__ __forceinline__ float bf2f(unsigned short b) {
  union { unsigned u; float f; } v; v.u = (unsigned)b << 16; return v.f;
}
__device__ __forceinline__ float fexp2(float x) { return __builtin_amdgcn_exp2f(x); }
__device__ __forceinline__ float frcp(float x)  { return __builtin_amdgcn_rcpf(x); }
__device__ __forceinline__ float sigm(float x)  { return frcp(1.f + fexp2(-1.44269504f * x)); }
__device__ __forceinline__ float tanh_(float x) { return 2.f * frcp(1.f + fexp2(-2.88539008f * x)) - 1.f; }
__device__ __forceinline__ char q8(float x, float s) {
  float v = fminf(fmaxf(x * s, -127.f), 127.f);
  return (char)(int)__builtin_rintf(v);
}
// h*s split into hi + lo/254 (lo in [-127,127] exactly since 0.5*254=127)
__device__ __forceinline__ void q8pair(float h, float s, char* hi, char* lo) {
  float hs = fminf(fmaxf(h * s, -127.f), 127.f);
  float hq = __builtin_rintf(hs);
  *hi = (char)(int)hq;
  *lo = (char)(int)__builtin_rintf((hs - hq) * 254.f);
}

// ---------------- initial state (mapping verified R1-R3) ----------------
// h[l][b][j] = M[l*1024 + b/2, (b&1)*256 + j]; h stored i8-pair at scale 31.75.
__global__ void init_state(const float* __restrict__ z,
                           const float* __restrict__ Wfh, const float* __restrict__ bfh,
                           const float* __restrict__ Wfc, const float* __restrict__ bfc,
                           char* __restrict__ h0h, char* __restrict__ h0l,
                           char* __restrict__ h1h, char* __restrict__ h1l,
                           float* __restrict__ c0s, float* __restrict__ c1s)
{
  int idx = blockIdx.x * 256 + threadIdx.x;
  int b = idx >> 8;
  int j = idx & 255;
  int col = ((b & 1) << 8) | j;
  const float* z0 = z + (size_t)(b >> 1) * ZDIM;
  const float* z1 = z + (size_t)(1024 + (b >> 1)) * ZDIM;
  float h0 = bfh[col], c0v = bfc[col], h1 = bfh[col], c1v = bfc[col];
  for (int k = 0; k < ZDIM; ++k) {
    float wh = Wfh[k * 512 + col];
    float wc = Wfc[k * 512 + col];
    float a = z0[k], bb = z1[k];
    h0  += a * wh;  c0v += a * wc;
    h1  += bb * wh; c1v += bb * wc;
  }
  char hi, lo;
  q8pair(h0, 31.75f, &hi, &lo); h0h[idx] = hi; h0l[idx] = lo;
  q8pair(h1, 31.75f, &hi, &lo); h1h[idx] = hi; h1l[idx] = lo;
  c0s[idx] = c0v; c1s[idx] = c1v;
}

// ---------------- per-output-column scales ----------------
__global__ void col_scales(const float* __restrict__ Whh0,
                           const float* __restrict__ Wih1, const float* __restrict__ Whh1,
                           float* __restrict__ cs0, float* __restrict__ qs0,
                           float* __restrict__ cs1, float* __restrict__ qs1)
{
  int c = blockIdx.x * 256 + threadIdx.x;   // 0..2047
  if (c < 1024) {
    float m = 0.f;
    for (int k = 0; k < 256; ++k) m = fmaxf(m, fabsf(Whh0[(size_t)k * G4 + c]));
    cs0[c] = m * (1.f / 16129.f);           // (m/127) * (1/127)
    qs0[c] = 127.f / m;
  } else {
    c -= 1024;
    float m = 0.f;
    for (int k = 0; k < 256; ++k) m = fmaxf(m, fabsf(Whh1[(size_t)k * G4 + c]));
    for (int k = 0; k < 256; ++k) m = fmaxf(m, fabsf(Wih1[(size_t)k * G4 + c]));
    cs1[c] = m * (1.f / 16129.f);
    qs1[c] = 127.f / m;
  }
}

// ------- i8 weight pack, order [kc][wave][tile][lane] (confirmed by R4) -----
// B-frag (16x16x64 i8): lane l holds W[k = kc*64 + (l>>4)*16 + j][n], j=0..15.
// tile i: gate g=i>>1, cc=i&1, ntile = g*16 + 2*w + cc.
// Layer0 K (256): Whh0. Layer1 K (512): 0..255 Whh1 (h1 first) | 256..511 Wih1.
__global__ void pack_i8(const float* __restrict__ Whh0,
                        const float* __restrict__ Wih1, const float* __restrict__ Whh1,
                        const float* __restrict__ qs0, const float* __restrict__ qs1,
                        char* __restrict__ p0, char* __restrict__ p1)
{
  int tt   = blockIdx.x * 4 + (threadIdx.x >> 6);   // 0..767
  int lane = threadIdx.x & 63;
  int l15 = lane & 15, lq = lane >> 4;
  union { char c[16]; uint4 u; } v;
  if (tt < 256) {                                   // layer0: 4 kc x 8 w x 8 i
    int kc = tt >> 6, w = (tt >> 3) & 7, i = tt & 7;
    int nt = (i >> 1) * 16 + 2 * w + (i & 1);
    int col = nt * 16 + l15;
    float q = qs0[col];
    for (int j = 0; j < 16; ++j) {
      int k = kc * 64 + lq * 16 + j;
      v.c[j] = q8(Whh0[(size_t)k * G4 + col], q);
    }
    *(uint4*)(p0 + (size_t)tt * 1024 + lane * 16) = v.u;
  } else {                                          // layer1: 8 kc x 8 w x 8 i
    int t1 = tt - 256;
    int kc = t1 >> 6, w = (t1 >> 3) & 7, i = t1 & 7;
    int nt = (i >> 1) * 16 + 2 * w + (i & 1);
    int col = nt * 16 + l15;
    float q = qs1[col];
    for (int j = 0; j < 16; ++j) {
      int k = kc * 64 + lq * 16 + j;
      float wv = (k < 256) ? Whh1[(size_t)k * G4 + col]
                           : Wih1[(size_t)(k - 256) * G4 + col];
      v.c[j] = q8(wv, q);
    }
    *(uint4*)(p1 + (size_t)t1 * 1024 + lane * 16) = v.u;
  }
}

// ---------------- persistent LSTM kernel ----------------
__global__ __launch_bounds__(NTH, 2) void lstm_run(
    const float* __restrict__ target,
    const char* __restrict__ p0, const char* __restrict__ p1,
    const float* __restrict__ bih0, const float* __restrict__ bhh0,
    const float* __restrict__ bih1, const float* __restrict__ bhh1,
    const float* __restrict__ Wih0,            // [8,1024] fp32 (x-path, exact)
    const float* __restrict__ Wout, const float* __restrict__ bout,
    const char* __restrict__ h0h, const char* __restrict__ h0l,
    const char* __restrict__ h1h, const char* __restrict__ h1l,
    const float* __restrict__ c0s, const float* __restrict__ c1s,
    const float* __restrict__ cs0, const float* __restrict__ cs1,
    float* __restrict__ out)
{
  // X blocked i8 (hi and lo planes): blk = k>>4 (0..15 = h1, 16..31 = h0),
  // element (m,k) at X[blk*16 + m], byte k&15. A-read = one 16B LDS load.
  __shared__ uint4 X4h[32 * 16];                   // 8 KB
  __shared__ uint4 X4l[32 * 16];                   // 8 KB
  __shared__ float Wih0_lds[DDIM * G4];            // 32 KB
  __shared__ unsigned short h1f[16 * H1STR];       // 8.25 KB
  __shared__ unsigned short woutT[8 * H1STR];      // 4.1 KB
  __shared__ float x_lds[16 * 8];                  // 0.5 KB
  __shared__ float pout[16][8][4];                 // 2 KB  (total ~62.9 KB)

  const int tid  = threadIdx.x;
  const int w    = tid >> 6;
  const int lane = tid & 63;
  const int l15  = lane & 15;
  const int lq   = lane >> 4;
  const int b0   = blockIdx.x * ROWS;
  char* Xch = (char*)X4h;
  char* Xcl = (char*)X4l;

  // ---- one-time staging ----
  {
    int m = tid & 15, blk = tid >> 4;              // 512 threads = 32 blks x 16 m
    const char* sh = (blk < 16) ? h1h : h0h;
    const char* sl = (blk < 16) ? h1l : h0l;
    int jblk = blk & 15;
    X4h[blk * 16 + m] = *(const uint4*)(sh + (size_t)(b0 + m) * HDIM + jblk * 16);
    X4l[blk * 16 + m] = *(const uint4*)(sl + (size_t)(b0 + m) * HDIM + jblk * 16);
  }
  for (int i = tid; i < DDIM * G4; i += NTH) Wih0_lds[i] = Wih0[i];
  for (int i = tid; i < HDIM * DDIM; i += NTH) {
    int k = i >> 3, d = i & 7;
    woutT[d * H1STR + k] = f2bf(Wout[i]);
  }

  const int myrow = lq * 4;
  const int jc0   = 32 * w + l15;
  float c0r[2][4], c1r[2][4];
  float bA0[8], bA1[8], csA0[8], csA1[8];          // flat [g*2+cc]
#pragma unroll
  for (int i = 0; i < 8; ++i) {
    int col = (i >> 1) * 256 + jc0 + 16 * (i & 1);
    bA0[i]  = bih0[col] + bhh0[col];
    bA1[i]  = bih1[col] + bhh1[col];
    csA0[i] = cs0[col];
    csA1[i] = cs1[col];
  }
#pragma unroll
  for (int cc = 0; cc < 2; ++cc) {
    int j = jc0 + cc * 16;
#pragma unroll
    for (int r = 0; r < 4; ++r) {
      c0r[cc][r] = c0s[(size_t)(b0 + myrow + r) * HDIM + j];
      c1r[cc][r] = c1s[(size_t)(b0 + myrow + r) * HDIM + j];
    }
  }
  const int opr = tid >> 5, opd = (tid >> 2) & 7, opq = tid & 3;
  const float bo_out = bout[tid & 7];

  const uint4* gw0 = (const uint4*)p0 + (size_t)w * 512 + lane;
  const uint4* gw1 = (const uint4*)p1 + (size_t)w * 512 + lane;

  uint4 bufA[8], bufB[8];
#define ISSUE8(BUF, PTR, KC) _Pragma("unroll") \
    for (int ii = 0; ii < 8; ++ii) BUF[ii] = (PTR)[(size_t)(KC) * 4096 + ii * 64];
#define MFMA8x2(BUF, AH, AL) _Pragma("unroll") \
    for (int ii = 0; ii < 8; ++ii) { \
      v4i bb = __builtin_bit_cast(v4i, BUF[ii]); \
      acch[ii] = __builtin_amdgcn_mfma_i32_16x16x64_i8(AH, bb, acch[ii], 0, 0, 0); \
      accl[ii] = __builtin_amdgcn_mfma_i32_16x16x64_i8(AL, bb, accl[ii], 0, 0, 0); \
    }
#define A0VH(KC) __builtin_bit_cast(v4i, X4h[(16 + (KC) * 4 + lq) * 16 + l15])
#define A0VL(KC) __builtin_bit_cast(v4i, X4l[(16 + (KC) * 4 + lq) * 16 + l15])
#define A1VH(KC) __builtin_bit_cast(v4i, X4h[((KC) * 4 + lq) * 16 + l15])
#define A1VL(KC) __builtin_bit_cast(v4i, X4l[((KC) * 4 + lq) * 16 + l15])

  ISSUE8(bufA, gw0, 0);            // prologue: L0 kc0/kc1 in flight
  ISSUE8(bufB, gw0, 1);

  __syncthreads();

  for (int t = 0; t < TSTEPS; ++t) {
    // ---- teacher-forced input (fp32) ----
    if (tid < 128) {
      int m = tid >> 3, d = tid & 7;
      x_lds[m * 8 + d] = (t == 0) ? 0.f
          : target[(size_t)(b0 + m) * (TSTEPS * DDIM) + (size_t)(t - 1) * DDIM + d];
    }

    const float sc0 = (t <= 1) ? 4.f : 1.f;        // h at scale 31.75 early
    const float sc1 = (t == 0) ? 4.f : 1.f;
    const float wq0 = (t == 0) ? 31.75f : 127.f;   // h0'(0) must match sc1 dequant

    // ================= layer 0: h0 @ Whh0, 4 K-groups =================
    v4i acch[8], accl[8];
    const v4i zi = {0, 0, 0, 0};
#pragma unroll
    for (int i = 0; i < 8; ++i) { acch[i] = zi; accl[i] = zi; }
    { v4i ah = A0VH(0), al = A0VL(0); MFMA8x2(bufA, ah, al); } ISSUE8(bufA, gw0, 2);
    { v4i ah = A0VH(1), al = A0VL(1); MFMA8x2(bufB, ah, al); } ISSUE8(bufB, gw0, 3);
    { v4i ah = A0VH(2), al = A0VL(2); MFMA8x2(bufA, ah, al); } ISSUE8(bufA, gw1, 0);
    { v4i ah = A0VH(3), al = A0VL(3); MFMA8x2(bufB, ah, al); } ISSUE8(bufB, gw1, 1);
    __syncthreads();   // (a) X h0-region reads + x-writes complete

    // ---- cell 0: dequant + exact fp32 x-path + activations ----
    {
      float xv[4][8];
#pragma unroll
      for (int r = 0; r < 4; ++r) {
        float4 plo = *(const float4*)&x_lds[(myrow + r) * 8];
        float4 phi = *(const float4*)&x_lds[(myrow + r) * 8 + 4];
        xv[r][0] = plo.x; xv[r][1] = plo.y; xv[r][2] = plo.z; xv[r][3] = plo.w;
        xv[r][4] = phi.x; xv[r][5] = phi.y; xv[r][6] = phi.z; xv[r][7] = phi.w;
      }
      float gf[8][4];
#pragma unroll
      for (int i = 0; i < 8; ++i) {
        float cs = csA0[i] * sc0;
#pragma unroll
        for (int r = 0; r < 4; ++r)
          gf[i][r] = ((float)acch[i][r] + (float)accl[i][r] * (1.f / 254.f)) * cs + bA0[i];
      }
#pragma unroll
      for (int d = 0; d < 8; ++d) {
        float w8[8];
#pragma unroll
        for (int i = 0; i < 8; ++i)
          w8[i] = Wih0_lds[d * G4 + (i >> 1) * 256 + jc0 + 16 * (i & 1)];
#pragma unroll
        for (int i = 0; i < 8; ++i)
#pragma unroll
          for (int r = 0; r < 4; ++r) gf[i][r] += xv[r][d] * w8[i];
      }
#pragma unroll
      for (int cc = 0; cc < 2; ++cc)
#pragma unroll
        for (int r = 0; r < 4; ++r) {
          float iv = sigm(gf[0 + cc][r]);
          float fv = sigm(gf[2 + cc][r]);
          float gv = tanh_(gf[4 + cc][r]);
          float ov = sigm(gf[6 + cc][r]);
          c0r[cc][r] = fv * c0r[cc][r] + iv * gv;
          char hi, lo;
          q8pair(ov * tanh_(c0r[cc][r]), wq0, &hi, &lo);
          int off = ((16 + 2 * w + cc) * 16 + myrow + r) * 16 + l15;
          Xch[off] = hi; Xcl[off] = lo;
        }
    }
    __syncthreads();   // (b) h0' i8 visible

    // ================= layer 1: [h1|h0'] @ W1, 8 K-groups =================
#pragma unroll
    for (int i = 0; i < 8; ++i) { acch[i] = zi; accl[i] = zi; }
    { v4i ah = A1VH(0), al = A1VL(0); MFMA8x2(bufA, ah, al); } ISSUE8(bufA, gw1, 2);
    { v4i ah = A1VH(1), al = A1VL(1); MFMA8x2(bufB, ah, al); } ISSUE8(bufB, gw1, 3);
    { v4i ah = A1VH(2), al = A1VL(2); MFMA8x2(bufA, ah, al); } ISSUE8(bufA, gw1, 4);
    { v4i ah = A1VH(3), al = A1VL(3); MFMA8x2(bufB, ah, al); } ISSUE8(bufB, gw1, 5);
    { v4i ah = A1VH(4), al = A1VL(4); MFMA8x2(bufA, ah, al); } ISSUE8(bufA, gw1, 6);
    { v4i ah = A1VH(5), al = A1VL(5); MFMA8x2(bufB, ah, al); } ISSUE8(bufB, gw1, 7);
    { v4i ah = A1VH(6), al = A1VL(6); MFMA8x2(bufA, ah, al); } ISSUE8(bufA, gw0, 0);
    { v4i ah = A1VH(7), al = A1VL(7); MFMA8x2(bufB, ah, al); } ISSUE8(bufB, gw0, 1);
    __syncthreads();   // (c) X reads done; h1 region may be overwritten

    // ---- cell 1 ----
#pragma unroll
    for (int cc = 0; cc < 2; ++cc)
#pragma unroll
      for (int r = 0; r < 4; ++r) {
        float di = ((float)acch[0 + cc][r] + (float)accl[0 + cc][r] * (1.f / 254.f));
        float df = ((float)acch[2 + cc][r] + (float)accl[2 + cc][r] * (1.f / 254.f));
        float dg = ((float)acch[4 + cc][r] + (float)accl[4 + cc][r] * (1.f / 254.f));
        float dv = ((float)acch[6 + cc][r] + (float)accl[6 + cc][r] * (1.f / 254.f));
        float iv = sigm(di * csA1[0 + cc] * sc1 + bA1[0 + cc]);
        float fv = sigm(df * csA1[2 + cc] * sc1 + bA1[2 + cc]);
        float gv = tanh_(dg * csA1[4 + cc] * sc1 + bA1[4 + cc]);
        float ov = sigm(dv * csA1[6 + cc] * sc1 + bA1[6 + cc]);
        c1r[cc][r] = fv * c1r[cc][r] + iv * gv;
        float h = ov * tanh_(c1r[cc][r]);
        char hi, lo;
        q8pair(h, 127.f, &hi, &lo);
        int off = ((2 * w + cc) * 16 + myrow + r) * 16 + l15;
        Xch[off] = hi; Xcl[off] = lo;
        h1f[(myrow + r) * H1STR + jc0 + cc * 16] = f2bf(h);
      }
    __syncthreads();   // (d) h1f visible

    // ---- out projection: out[b,t,:] = h1 @ Wout + bout ----
    {
      float s = 0.f;
#pragma unroll
      for (int i = 0; i < 16; ++i) {
        int k = i * 16 + opq * 4;
        ushort4 hx = *(const ushort4*)&h1f[opr * H1STR + k];
        ushort4 wx = *(const ushort4*)&woutT[opd * H1STR + k];
        s += bf2f(hx.x) * bf2f(wx.x) + bf2f(hx.y) * bf2f(wx.y)
           + bf2f(hx.z) * bf2f(wx.z) + bf2f(hx.w) * bf2f(wx.w);
      }
      pout[opr][opd][opq] = s;
    }
    __syncthreads();   // (e) partials visible
    if (tid < 128) {
      int m = tid >> 3, d = tid & 7;
      float v = pout[m][d][0] + pout[m][d][1] + pout[m][d][2] + pout[m][d][3] + bo_out;
      out[(size_t)(b0 + m) * (TSTEPS * DDIM) + (size_t)t * DDIM + d] = v;
    }
  }
#undef ISSUE8
#undef MFMA8x2
#undef A0VH
#undef A0VL
#undef A1VH
#undef A1VL
}

extern "C" void kernel_launch(void* const* d_in, const int* in_sizes, int n_in,
                              void* d_out, int out_size, void* d_ws, size_t ws_size,
                              hipStream_t stream) {
  const float* z    = (const float*)d_in[0];
  const float* tgt  = (const float*)d_in[1];
  const float* Wfh  = (const float*)d_in[2];
  const float* bfh  = (const float*)d_in[3];
  const float* Wfc  = (const float*)d_in[4];
  const float* bfc  = (const float*)d_in[5];
  const float* Wih0 = (const float*)d_in[6];
  const float* Whh0 = (const float*)d_in[7];
  const float* bih0 = (const float*)d_in[8];
  const float* bhh0 = (const float*)d_in[9];
  const float* Wih1 = (const float*)d_in[10];
  const float* Whh1 = (const float*)d_in[11];
  const float* bih1 = (const float*)d_in[12];
  const float* bhh1 = (const float*)d_in[13];
  const float* Wout = (const float*)d_in[14];
  const float* bout = (const float*)d_in[15];

  // ws layout (bytes), total ~7.09 MB
  char* ws = (char*)d_ws;
  char*  p0   = ws;                                  // 262,144
  char*  p1   = ws + 262144;                         // 524,288
  char*  h0h  = ws + 786432;                         // 524,288
  char*  h0l  = ws + 1310720;                        // 524,288
  char*  h1h  = ws + 1835008;                        // 524,288
  char*  h1l  = ws + 2359296;                        // 524,288
  float* c0s  = (float*)(ws + 2883584);              // 2,097,152
  float* c1s  = (float*)(ws + 4980736);              // 2,097,152
  float* cs0  = (float*)(ws + 7077888);              // 4,096
  float* qs0  = (float*)(ws + 7081984);              // 4,096
  float* cs1  = (float*)(ws + 7086080);              // 4,096
  float* qs1  = (float*)(ws + 7090176);              // 4,096

  hipLaunchKernelGGL(init_state, dim3(BSZ * HDIM / 256), dim3(256), 0, stream,
                     z, Wfh, bfh, Wfc, bfc, h0h, h0l, h1h, h1l, c0s, c1s);
  hipLaunchKernelGGL(col_scales, dim3(8), dim3(256), 0, stream,
                     Whh0, Wih1, Whh1, cs0, qs0, cs1, qs1);
  hipLaunchKernelGGL(pack_i8, dim3(192), dim3(256), 0, stream,
                     Whh0, Wih1, Whh1, qs0, qs1, p0, p1);
  hipLaunchKernelGGL(lstm_run, dim3(NWG), dim3(NTH), 0, stream,
                     tgt, p0, p1, bih0, bhh0, bih1, bhh1, Wih0, Wout, bout,
                     h0h, h0l, h1h, h1l, c0s, c1s, cs0, cs1, (float*)d_out);
}

// Round 6
// 6527.402 us; speedup vs baseline: 1.0178x; 1.0178x over previous
//
#include <hip/hip_runtime.h>
#include <cstddef>
#include <cstdint>

// 2-layer LSTM decoder, B=2048, Z=64, H=256, D=8, T=250. fp32 in/out.
//
// R6 = R5 (i8 weight stream + h hi/lo split, absmax 2.2e-3 verified) with the
// register budget fixed. R5's __launch_bounds__(512,2) made the compiler cap
// at 128 VGPRs (16-wave/CU occupancy target) while live demand is ~240
// -> 10 GB of scratch spill traffic (FETCH_SIZE 9.96e6 KB) = the whole loss.
// Changes:
//  1. __launch_bounds__(512, 1): 1 WG/CU -> 2 waves/EU -> 256-VGPR cap.
//  2. cell-0 restructured per-cc (gate temporaries 32 -> 16 regs peak).
// Everything else byte-identical to R5.

#define BSZ    2048
#define ZDIM   64
#define HDIM   256
#define DDIM   8
#define TSTEPS 250
#define ROWS   16
#define NWG    (BSZ / ROWS)   // 128
#define NTH    512            // 8 waves
#define G4     1024
#define H1STR  264            // h1f/woutT row stride (shorts)

typedef __attribute__((ext_vector_type(4))) int   v4i;

__device__ __forceinline__ unsigned short f2bf(float x) {   // RNE f32->bf16
  union { float f; unsigned u; } v; v.f = x;
  unsigned r = v.u + 0x7fff + ((v.u >> 16) & 1);
  return (unsigned short)(r >> 16);
}
__device__ __forceinline__ float bf2f(unsigned short b) {
  union { unsigned u; float f; } v; v.u = (unsigned)b << 16; return v.f;
}
__device__ __forceinline__ float fexp2(float x) { return __builtin_amdgcn_exp2f(x); }
__device__ __forceinline__ float frcp(float x)  { return __builtin_amdgcn_rcpf(x); }
__device__ __forceinline__ float sigm(float x)  { return frcp(1.f + fexp2(-1.44269504f * x)); }
__device__ __forceinline__ float tanh_(float x) { return 2.f * frcp(1.f + fexp2(-2.88539008f * x)) - 1.f; }
__device__ __forceinline__ char q8(float x, float s) {
  float v = fminf(fmaxf(x * s, -127.f), 127.f);
  return (char)(int)__builtin_rintf(v);
}
// h*s split into hi + lo/254 (lo in [-127,127] exactly since 0.5*254=127)
__device__ __forceinline__ void q8pair(float h, float s, char* hi, char* lo) {
  float hs = fminf(fmaxf(h * s, -127.f), 127.f);
  float hq = __builtin_rintf(hs);
  *hi = (char)(int)hq;
  *lo = (char)(int)__builtin_rintf((hs - hq) * 254.f);
}

// ---------------- initial state (mapping verified R1-R5) ----------------
// h[l][b][j] = M[l*1024 + b/2, (b&1)*256 + j]; h stored i8-pair at scale 31.75.
__global__ void init_state(const float* __restrict__ z,
                           const float* __restrict__ Wfh, const float* __restrict__ bfh,
                           const float* __restrict__ Wfc, const float* __restrict__ bfc,
                           char* __restrict__ h0h, char* __restrict__ h0l,
                           char* __restrict__ h1h, char* __restrict__ h1l,
                           float* __restrict__ c0s, float* __restrict__ c1s)
{
  int idx = blockIdx.x * 256 + threadIdx.x;
  int b = idx >> 8;
  int j = idx & 255;
  int col = ((b & 1) << 8) | j;
  const float* z0 = z + (size_t)(b >> 1) * ZDIM;
  const float* z1 = z + (size_t)(1024 + (b >> 1)) * ZDIM;
  float h0 = bfh[col], c0v = bfc[col], h1 = bfh[col], c1v = bfc[col];
  for (int k = 0; k < ZDIM; ++k) {
    float wh = Wfh[k * 512 + col];
    float wc = Wfc[k * 512 + col];
    float a = z0[k], bb = z1[k];
    h0  += a * wh;  c0v += a * wc;
    h1  += bb * wh; c1v += bb * wc;
  }
  char hi, lo;
  q8pair(h0, 31.75f, &hi, &lo); h0h[idx] = hi; h0l[idx] = lo;
  q8pair(h1, 31.75f, &hi, &lo); h1h[idx] = hi; h1l[idx] = lo;
  c0s[idx] = c0v; c1s[idx] = c1v;
}

// ---------------- per-output-column scales ----------------
__global__ void col_scales(const float* __restrict__ Whh0,
                           const float* __restrict__ Wih1, const float* __restrict__ Whh1,
                           float* __restrict__ cs0, float* __restrict__ qs0,
                           float* __restrict__ cs1, float* __restrict__ qs1)
{
  int c = blockIdx.x * 256 + threadIdx.x;   // 0..2047
  if (c < 1024) {
    float m = 0.f;
    for (int k = 0; k < 256; ++k) m = fmaxf(m, fabsf(Whh0[(size_t)k * G4 + c]));
    cs0[c] = m * (1.f / 16129.f);           // (m/127) * (1/127)
    qs0[c] = 127.f / m;
  } else {
    c -= 1024;
    float m = 0.f;
    for (int k = 0; k < 256; ++k) m = fmaxf(m, fabsf(Whh1[(size_t)k * G4 + c]));
    for (int k = 0; k < 256; ++k) m = fmaxf(m, fabsf(Wih1[(size_t)k * G4 + c]));
    cs1[c] = m * (1.f / 16129.f);
    qs1[c] = 127.f / m;
  }
}

// ------- i8 weight pack, order [kc][wave][tile][lane] (verified R4/R5) -----
// B-frag (16x16x64 i8): lane l holds W[k = kc*64 + (l>>4)*16 + j][n], j=0..15.
// tile i: gate g=i>>1, cc=i&1, ntile = g*16 + 2*w + cc.
// Layer0 K (256): Whh0. Layer1 K (512): 0..255 Whh1 (h1 first) | 256..511 Wih1.
__global__ void pack_i8(const float* __restrict__ Whh0,
                        const float* __restrict__ Wih1, const float* __restrict__ Whh1,
                        const float* __restrict__ qs0, const float* __restrict__ qs1,
                        char* __restrict__ p0, char* __restrict__ p1)
{
  int tt   = blockIdx.x * 4 + (threadIdx.x >> 6);   // 0..767
  int lane = threadIdx.x & 63;
  int l15 = lane & 15, lq = lane >> 4;
  union { char c[16]; uint4 u; } v;
  if (tt < 256) {                                   // layer0: 4 kc x 8 w x 8 i
    int kc = tt >> 6, w = (tt >> 3) & 7, i = tt & 7;
    int nt = (i >> 1) * 16 + 2 * w + (i & 1);
    int col = nt * 16 + l15;
    float q = qs0[col];
    for (int j = 0; j < 16; ++j) {
      int k = kc * 64 + lq * 16 + j;
      v.c[j] = q8(Whh0[(size_t)k * G4 + col], q);
    }
    *(uint4*)(p0 + (size_t)tt * 1024 + lane * 16) = v.u;
  } else {                                          // layer1: 8 kc x 8 w x 8 i
    int t1 = tt - 256;
    int kc = t1 >> 6, w = (t1 >> 3) & 7, i = t1 & 7;
    int nt = (i >> 1) * 16 + 2 * w + (i & 1);
    int col = nt * 16 + l15;
    float q = qs1[col];
    for (int j = 0; j < 16; ++j) {
      int k = kc * 64 + lq * 16 + j;
      float wv = (k < 256) ? Whh1[(size_t)k * G4 + col]
                           : Wih1[(size_t)(k - 256) * G4 + col];
      v.c[j] = q8(wv, q);
    }
    *(uint4*)(p1 + (size_t)t1 * 1024 + lane * 16) = v.u;
  }
}

// ---------------- persistent LSTM kernel ----------------
// launch_bounds(512, 1): 1 WG/CU -> 2 waves/EU -> 256-VGPR cap (demand ~240,
// no spills). R5's (512,2) capped at 128 and spilled 10 GB.
__global__ __launch_bounds__(NTH, 1) void lstm_run(
    const float* __restrict__ target,
    const char* __restrict__ p0, const char* __restrict__ p1,
    const float* __restrict__ bih0, const float* __restrict__ bhh0,
    const float* __restrict__ bih1, const float* __restrict__ bhh1,
    const float* __restrict__ Wih0,            // [8,1024] fp32 (x-path, exact)
    const float* __restrict__ Wout, const float* __restrict__ bout,
    const char* __restrict__ h0h, const char* __restrict__ h0l,
    const char* __restrict__ h1h, const char* __restrict__ h1l,
    const float* __restrict__ c0s, const float* __restrict__ c1s,
    const float* __restrict__ cs0, const float* __restrict__ cs1,
    float* __restrict__ out)
{
  // X blocked i8 (hi and lo planes): blk = k>>4 (0..15 = h1, 16..31 = h0),
  // element (m,k) at X[blk*16 + m], byte k&15. A-read = one 16B LDS load.
  __shared__ uint4 X4h[32 * 16];                   // 8 KB
  __shared__ uint4 X4l[32 * 16];                   // 8 KB
  __shared__ float Wih0_lds[DDIM * G4];            // 32 KB
  __shared__ unsigned short h1f[16 * H1STR];       // 8.25 KB
  __shared__ unsigned short woutT[8 * H1STR];      // 4.1 KB
  __shared__ float x_lds[16 * 8];                  // 0.5 KB
  __shared__ float pout[16][8][4];                 // 2 KB  (total ~62.9 KB)

  const int tid  = threadIdx.x;
  const int w    = tid >> 6;
  const int lane = tid & 63;
  const int l15  = lane & 15;
  const int lq   = lane >> 4;
  const int b0   = blockIdx.x * ROWS;
  char* Xch = (char*)X4h;
  char* Xcl = (char*)X4l;

  // ---- one-time staging ----
  {
    int m = tid & 15, blk = tid >> 4;              // 512 threads = 32 blks x 16 m
    const char* sh = (blk < 16) ? h1h : h0h;
    const char* sl = (blk < 16) ? h1l : h0l;
    int jblk = blk & 15;
    X4h[blk * 16 + m] = *(const uint4*)(sh + (size_t)(b0 + m) * HDIM + jblk * 16);
    X4l[blk * 16 + m] = *(const uint4*)(sl + (size_t)(b0 + m) * HDIM + jblk * 16);
  }
  for (int i = tid; i < DDIM * G4; i += NTH) Wih0_lds[i] = Wih0[i];
  for (int i = tid; i < HDIM * DDIM; i += NTH) {
    int k = i >> 3, d = i & 7;
    woutT[d * H1STR + k] = f2bf(Wout[i]);
  }

  const int myrow = lq * 4;
  const int jc0   = 32 * w + l15;
  float c0r[2][4], c1r[2][4];
  float bA0[8], bA1[8], csA0[8], csA1[8];          // flat [g*2+cc]
#pragma unroll
  for (int i = 0; i < 8; ++i) {
    int col = (i >> 1) * 256 + jc0 + 16 * (i & 1);
    bA0[i]  = bih0[col] + bhh0[col];
    bA1[i]  = bih1[col] + bhh1[col];
    csA0[i] = cs0[col];
    csA1[i] = cs1[col];
  }
#pragma unroll
  for (int cc = 0; cc < 2; ++cc) {
    int j = jc0 + cc * 16;
#pragma unroll
    for (int r = 0; r < 4; ++r) {
      c0r[cc][r] = c0s[(size_t)(b0 + myrow + r) * HDIM + j];
      c1r[cc][r] = c1s[(size_t)(b0 + myrow + r) * HDIM + j];
    }
  }
  const int opr = tid >> 5, opd = (tid >> 2) & 7, opq = tid & 3;
  const float bo_out = bout[tid & 7];

  const uint4* gw0 = (const uint4*)p0 + (size_t)w * 512 + lane;
  const uint4* gw1 = (const uint4*)p1 + (size_t)w * 512 + lane;

  uint4 bufA[8], bufB[8];
#define ISSUE8(BUF, PTR, KC) _Pragma("unroll") \
    for (int ii = 0; ii < 8; ++ii) BUF[ii] = (PTR)[(size_t)(KC) * 4096 + ii * 64];
#define MFMA8x2(BUF, AH, AL) _Pragma("unroll") \
    for (int ii = 0; ii < 8; ++ii) { \
      v4i bb = __builtin_bit_cast(v4i, BUF[ii]); \
      acch[ii] = __builtin_amdgcn_mfma_i32_16x16x64_i8(AH, bb, acch[ii], 0, 0, 0); \
      accl[ii] = __builtin_amdgcn_mfma_i32_16x16x64_i8(AL, bb, accl[ii], 0, 0, 0); \
    }
#define A0VH(KC) __builtin_bit_cast(v4i, X4h[(16 + (KC) * 4 + lq) * 16 + l15])
#define A0VL(KC) __builtin_bit_cast(v4i, X4l[(16 + (KC) * 4 + lq) * 16 + l15])
#define A1VH(KC) __builtin_bit_cast(v4i, X4h[((KC) * 4 + lq) * 16 + l15])
#define A1VL(KC) __builtin_bit_cast(v4i, X4l[((KC) * 4 + lq) * 16 + l15])

  ISSUE8(bufA, gw0, 0);            // prologue: L0 kc0/kc1 in flight
  ISSUE8(bufB, gw0, 1);

  __syncthreads();

  for (int t = 0; t < TSTEPS; ++t) {
    // ---- teacher-forced input (fp32) ----
    if (tid < 128) {
      int m = tid >> 3, d = tid & 7;
      x_lds[m * 8 + d] = (t == 0) ? 0.f
          : target[(size_t)(b0 + m) * (TSTEPS * DDIM) + (size_t)(t - 1) * DDIM + d];
    }

    const float sc0 = (t <= 1) ? 4.f : 1.f;        // h at scale 31.75 early
    const float sc1 = (t == 0) ? 4.f : 1.f;
    const float wq0 = (t == 0) ? 31.75f : 127.f;   // h0'(0) must match sc1 dequant

    // ================= layer 0: h0 @ Whh0, 4 K-groups =================
    v4i acch[8], accl[8];
    const v4i zi = {0, 0, 0, 0};
#pragma unroll
    for (int i = 0; i < 8; ++i) { acch[i] = zi; accl[i] = zi; }
    { v4i ah = A0VH(0), al = A0VL(0); MFMA8x2(bufA, ah, al); } ISSUE8(bufA, gw0, 2);
    { v4i ah = A0VH(1), al = A0VL(1); MFMA8x2(bufB, ah, al); } ISSUE8(bufB, gw0, 3);
    { v4i ah = A0VH(2), al = A0VL(2); MFMA8x2(bufA, ah, al); } ISSUE8(bufA, gw1, 0);
    { v4i ah = A0VH(3), al = A0VL(3); MFMA8x2(bufB, ah, al); } ISSUE8(bufB, gw1, 1);
    __syncthreads();   // (a) X h0-region reads + x-writes complete

    // ---- cell 0: dequant + exact fp32 x-path + activations (per-cc) ----
    {
      float xv[4][8];
#pragma unroll
      for (int r = 0; r < 4; ++r) {
        float4 plo = *(const float4*)&x_lds[(myrow + r) * 8];
        float4 phi = *(const float4*)&x_lds[(myrow + r) * 8 + 4];
        xv[r][0] = plo.x; xv[r][1] = plo.y; xv[r][2] = plo.z; xv[r][3] = plo.w;
        xv[r][4] = phi.x; xv[r][5] = phi.y; xv[r][6] = phi.z; xv[r][7] = phi.w;
      }
#pragma unroll
      for (int cc = 0; cc < 2; ++cc) {
        float gf4[4][4];                           // [gate][row], 16 regs live
#pragma unroll
        for (int g = 0; g < 4; ++g) {
          int i = g * 2 + cc;
          float cs = csA0[i] * sc0;
#pragma unroll
          for (int r = 0; r < 4; ++r)
            gf4[g][r] = ((float)acch[i][r] + (float)accl[i][r] * (1.f / 254.f)) * cs + bA0[i];
        }
#pragma unroll
        for (int d = 0; d < 8; ++d) {
          float w4[4];
#pragma unroll
          for (int g = 0; g < 4; ++g)
            w4[g] = Wih0_lds[d * G4 + g * 256 + jc0 + 16 * cc];
#pragma unroll
          for (int g = 0; g < 4; ++g)
#pragma unroll
            for (int r = 0; r < 4; ++r) gf4[g][r] += xv[r][d] * w4[g];
        }
#pragma unroll
        for (int r = 0; r < 4; ++r) {
          float iv = sigm(gf4[0][r]);
          float fv = sigm(gf4[1][r]);
          float gv = tanh_(gf4[2][r]);
          float ov = sigm(gf4[3][r]);
          c0r[cc][r] = fv * c0r[cc][r] + iv * gv;
          char hi, lo;
          q8pair(ov * tanh_(c0r[cc][r]), wq0, &hi, &lo);
          int off = ((16 + 2 * w + cc) * 16 + myrow + r) * 16 + l15;
          Xch[off] = hi; Xcl[off] = lo;
        }
      }
    }
    __syncthreads();   // (b) h0' i8 visible

    // ================= layer 1: [h1|h0'] @ W1, 8 K-groups =================
#pragma unroll
    for (int i = 0; i < 8; ++i) { acch[i] = zi; accl[i] = zi; }
    { v4i ah = A1VH(0), al = A1VL(0); MFMA8x2(bufA, ah, al); } ISSUE8(bufA, gw1, 2);
    { v4i ah = A1VH(1), al = A1VL(1); MFMA8x2(bufB, ah, al); } ISSUE8(bufB, gw1, 3);
    { v4i ah = A1VH(2), al = A1VL(2); MFMA8x2(bufA, ah, al); } ISSUE8(bufA, gw1, 4);
    { v4i ah = A1VH(3), al = A1VL(3); MFMA8x2(bufB, ah, al); } ISSUE8(bufB, gw1, 5);
    { v4i ah = A1VH(4), al = A1VL(4); MFMA8x2(bufA, ah, al); } ISSUE8(bufA, gw1, 6);
    { v4i ah = A1VH(5), al = A1VL(5); MFMA8x2(bufB, ah, al); } ISSUE8(bufB, gw1, 7);
    { v4i ah = A1VH(6), al = A1VL(6); MFMA8x2(bufA, ah, al); } ISSUE8(bufA, gw0, 0);
    { v4i ah = A1VH(7), al = A1VL(7); MFMA8x2(bufB, ah, al); } ISSUE8(bufB, gw0, 1);
    __syncthreads();   // (c) X reads done; h1 region may be overwritten

    // ---- cell 1 ----
#pragma unroll
    for (int cc = 0; cc < 2; ++cc)
#pragma unroll
      for (int r = 0; r < 4; ++r) {
        float di = ((float)acch[0 + cc][r] + (float)accl[0 + cc][r] * (1.f / 254.f));
        float df = ((float)acch[2 + cc][r] + (float)accl[2 + cc][r] * (1.f / 254.f));
        float dg = ((float)acch[4 + cc][r] + (float)accl[4 + cc][r] * (1.f / 254.f));
        float dv = ((float)acch[6 + cc][r] + (float)accl[6 + cc][r] * (1.f / 254.f));
        float iv = sigm(di * csA1[0 + cc] * sc1 + bA1[0 + cc]);
        float fv = sigm(df * csA1[2 + cc] * sc1 + bA1[2 + cc]);
        float gv = tanh_(dg * csA1[4 + cc] * sc1 + bA1[4 + cc]);
        float ov = sigm(dv * csA1[6 + cc] * sc1 + bA1[6 + cc]);
        c1r[cc][r] = fv * c1r[cc][r] + iv * gv;
        float h = ov * tanh_(c1r[cc][r]);
        char hi, lo;
        q8pair(h, 127.f, &hi, &lo);
        int off = ((2 * w + cc) * 16 + myrow + r) * 16 + l15;
        Xch[off] = hi; Xcl[off] = lo;
        h1f[(myrow + r) * H1STR + jc0 + cc * 16] = f2bf(h);
      }
    __syncthreads();   // (d) h1f visible

    // ---- out projection: out[b,t,:] = h1 @ Wout + bout ----
    {
      float s = 0.f;
#pragma unroll
      for (int i = 0; i < 16; ++i) {
        int k = i * 16 + opq * 4;
        ushort4 hx = *(const ushort4*)&h1f[opr * H1STR + k];
        ushort4 wx = *(const ushort4*)&woutT[opd * H1STR + k];
        s += bf2f(hx.x) * bf2f(wx.x) + bf2f(hx.y) * bf2f(wx.y)
           + bf2f(hx.z) * bf2f(wx.z) + bf2f(hx.w) * bf2f(wx.w);
      }
      pout[opr][opd][opq] = s;
    }
    __syncthreads();   // (e) partials visible
    if (tid < 128) {
      int m = tid >> 3, d = tid & 7;
      float v = pout[m][d][0] + pout[m][d][1] + pout[m][d][2] + pout[m][d][3] + bo_out;
      out[(size_t)(b0 + m) * (TSTEPS * DDIM) + (size_t)t * DDIM + d] = v;
    }
  }
#undef ISSUE8
#undef MFMA8x2
#undef A0VH
#undef A0VL
#undef A1VH
#undef A1VL
}

extern "C" void kernel_launch(void* const* d_in, const int* in_sizes, int n_in,
                              void* d_out, int out_size, void* d_ws, size_t ws_size,
                              hipStream_t stream) {
  const float* z    = (const float*)d_in[0];
  const float* tgt  = (const float*)d_in[1];
  const float* Wfh  = (const float*)d_in[2];
  const float* bfh  = (const float*)d_in[3];
  const float* Wfc  = (const float*)d_in[4];
  const float* bfc  = (const float*)d_in[5];
  const float* Wih0 = (const float*)d_in[6];
  const float* Whh0 = (const float*)d_in[7];
  const float* bih0 = (const float*)d_in[8];
  const float* bhh0 = (const float*)d_in[9];
  const float* Wih1 = (const float*)d_in[10];
  const float* Whh1 = (const float*)d_in[11];
  const float* bih1 = (const float*)d_in[12];
  const float* bhh1 = (const float*)d_in[13];
  const float* Wout = (const float*)d_in[14];
  const float* bout = (const float*)d_in[15];

  // ws layout (bytes), total ~7.09 MB
  char* ws = (char*)d_ws;
  char*  p0   = ws;                                  // 262,144
  char*  p1   = ws + 262144;                         // 524,288
  char*  h0h  = ws + 786432;                         // 524,288
  char*  h0l  = ws + 1310720;                        // 524,288
  char*  h1h  = ws + 1835008;                        // 524,288
  char*  h1l  = ws + 2359296;                        // 524,288
  float* c0s  = (float*)(ws + 2883584);              // 2,097,152
  float* c1s  = (float*)(ws + 4980736);              // 2,097,152
  float* cs0  = (float*)(ws + 7077888);              // 4,096
  float* qs0  = (float*)(ws + 7081984);              // 4,096
  float* cs1  = (float*)(ws + 7086080);              // 4,096
  float* qs1  = (float*)(ws + 7090176);              // 4,096

  hipLaunchKernelGGL(init_state, dim3(BSZ * HDIM / 256), dim3(256), 0, stream,
                     z, Wfh, bfh, Wfc, bfc, h0h, h0l, h1h, h1l, c0s, c1s);
  hipLaunchKernelGGL(col_scales, dim3(8), dim3(256), 0, stream,
                     Whh0, Wih1, Whh1, cs0, qs0, cs1, qs1);
  hipLaunchKernelGGL(pack_i8, dim3(192), dim3(256), 0, stream,
                     Whh0, Wih1, Whh1, qs0, qs1, p0, p1);
  hipLaunchKernelGGL(lstm_run, dim3(NWG), dim3(NTH), 0, stream,
                     tgt, p0, p1, bih0, bhh0, bih1, bhh1, Wih0, Wout, bout,
                     h0h, h0l, h1h, h1l, c0s, c1s, cs0, cs1, (float*)d_out);
}